// Round 2
// baseline (499.255 us; speedup 1.0000x reference)
//
#include <hip/hip_runtime.h>
#include <cstdint>

#define SEQ 512
#define BATCH 2048
#define HID 50
#define BB 8              // batches per block
#define NTHR 256          // 4 waves: 0,1 = L1 (tiles 0-6 / 6-12), 2,3 = L2 (same)
#define NBLK (BATCH / BB) // 256 blocks -> 1 per CU, 1 wave per SIMD
#define NT 13             // gate-row tiles of 16 (200 -> 208, permuted rows)
#define NTW 7             // tiles per wave; bases 0 and 6; tile 6 duplicated (dedup'd in FC)
#define S1H 80            // u1 stride halves: 40 dwords === 8 (mod 32)
#define S2H 144           // u2 stride halves: 72 dwords === 8 (mod 32)

typedef _Float16 f16;
typedef _Float16 v8h __attribute__((ext_vector_type(8)));
typedef float    v4f __attribute__((ext_vector_type(4)));

#if __has_builtin(__builtin_amdgcn_exp2f)
#define EXP2F(x) __builtin_amdgcn_exp2f(x)
#else
#define EXP2F(x) exp2f(x)
#endif
#define RCPF(x) __builtin_amdgcn_rcpf(x)
#define LOG2E 1.44269504f
#define MFMA(A,B,C) __builtin_amdgcn_mfma_f32_16x16x32_f16(A, B, C, 0, 0, 0)

// Row permutation (validated R5-R11): tile tt, in-tile row rho -> orig W row
// (rho%4)*50 + tt*4 + rho/4.  C layout (col=lane&15, row=(lane>>4)*4+reg)
// puts [i,f,g,o] of unit tt*4+q, batch col&7 in one lane's 4 C-regs.
// R2 structure: 4 waves only. Each wave owns 7 tiles via 7 accumulators;
// B cols = 8 batches x 2 copies; lane mb<8 reads acc[s] (tile base+s),
// mb>=8 reads acc[4+s] (tile base+4+s) -> 4 unit-updates per lane.
// Tile 6 is computed by both waves of a pair (identical values; FC dedup'd).
// Biases ride constant-1.0 u-column (k=54 / k=100); gate rows pre-scaled
// (i,f,o: -log2e; g: +2log2e) so the update uses raw v_exp_f32.

__global__ __launch_bounds__(NTHR, 1) void lstm2_fused(
    const float* __restrict__ x,
    const float* __restrict__ w_ih1, const float* __restrict__ w_hh1,
    const float* __restrict__ b_ih1, const float* __restrict__ b_hh1,
    const float* __restrict__ w_ih2, const float* __restrict__ w_hh2,
    const float* __restrict__ b_ih2, const float* __restrict__ b_hh2,
    const float* __restrict__ w_fc, const float* __restrict__ b_fc,
    float* __restrict__ out)
{
    __shared__ __align__(16) f16 u1h[2][BB * S1H];
    __shared__ __align__(16) f16 u2h[2][BB * S2H];
    __shared__ float fcw[2][2][BB];

    const int tid  = threadIdx.x;
    const int wv   = tid >> 6;        // 0..3
    const int lane = tid & 63;
    const int mb   = lane & 15;       // A-row-in-tile | C col
    const int q    = lane >> 4;       // quad
    const int bbase = blockIdx.x * BB;

    const bool grpB = (wv >= 2);              // waves 2,3: L2
    const int  base = (wv & 1) ? 6 : 0;       // tile base for this wave

    const bool hiHalf = (mb >= 8);
    const int  b_me   = mb & 7;               // batch: B-col AND update identity
    const int  gidx   = mb & 3;               // gate of this lane's A rows
    const float sc    = (gidx == 2) ? (2.0f * LOG2E) : (-LOG2E);

    // ---- per-slot packed update identity (slot s: lo tile base+s, hi tile base+4+s) ----
    int   u_s[4];
    bool  vw_s[4];
    float wfcv[4];
#pragma unroll
    for (int s4 = 0; s4 < 4; ++s4) {
        const int  tsel = base + (hiHalf ? 4 + s4 : s4);
        const bool vs   = !(hiHalf && s4 == 3);          // hi slot 3 doesn't exist
        const int  u    = tsel * 4 + q;
        vw_s[s4] = vs && (u < HID);
        u_s[s4]  = u;
        wfcv[s4] = 0.0f;
        if (grpB && vw_s[s4] && !(base == 6 && tsel == 6))  // dedup duplicated tile 6
            wfcv[s4] = w_fc[u];
    }
    const float bfc = b_fc[0];
    float cst[4] = {0.f, 0.f, 0.f, 0.f};

    // ---- weight-stationary A fragments (scaled, bias column) ----
    v8h Af[NTW][4];                   // L1 waves use kt 0..1, L2 waves kt 0..3
    if (!grpB) {
#pragma unroll
        for (int t = 0; t < NTW; ++t) {
            const int tt = base + t;
            const int ru = tt * 4 + (mb >> 2);
            const bool rv = (ru < HID);
            const int R = gidx * HID + ru;
#pragma unroll
            for (int kt = 0; kt < 2; ++kt) {
                v8h f;
#pragma unroll
                for (int j = 0; j < 8; ++j) {
                    const int kk = kt * 32 + q * 8 + j;
                    float v = 0.0f;
                    if (rv) {
                        if (kk < 4) v = w_ih1[R * 4 + kk];
                        else if (kk < 54) v = w_hh1[R * HID + (kk - 4)];
                        else if (kk == 54) v = b_ih1[R] + b_hh1[R];
                    }
                    f[j] = (f16)(v * sc);
                }
                Af[t][kt] = f;
            }
        }
    } else {
#pragma unroll
        for (int t = 0; t < NTW; ++t) {
            const int tt = base + t;
            const int ru = tt * 4 + (mb >> 2);
            const bool rv = (ru < HID);
            const int R = gidx * HID + ru;
#pragma unroll
            for (int kt = 0; kt < 4; ++kt) {
                v8h f;
#pragma unroll
                for (int j = 0; j < 8; ++j) {
                    const int kk = kt * 32 + q * 8 + j;
                    float v = 0.0f;
                    if (rv) {
                        if (kk < HID) v = w_ih2[R * HID + kk];
                        else if (kk < 2 * HID) v = w_hh2[R * HID + (kk - HID)];
                        else if (kk == 100) v = b_ih2[R] + b_hh2[R];
                    }
                    f[j] = (f16)(v * sc);
                }
                Af[t][kt] = f;
            }
        }
    }

    // ---- LDS init ----
    for (int idx = tid; idx < 2 * BB * S1H; idx += NTHR) ((f16*)u1h)[idx] = (f16)0.0f;
    for (int idx = tid; idx < 2 * BB * S2H; idx += NTHR) ((f16*)u2h)[idx] = (f16)0.0f;
    if (tid < 32) ((float*)fcw)[tid] = 0.0f;
    __syncthreads();
    if (tid < BB) {   // x(0) -> u1 parity 0
        const float4 x0 = *reinterpret_cast<const float4*>(x + (size_t)(bbase + tid) * 4);
        f16 p[4] = {(f16)x0.x, (f16)x0.y, (f16)x0.z, (f16)x0.w};
        *reinterpret_cast<uint2*>(&u1h[0][tid * S1H]) = *reinterpret_cast<uint2*>(p);
    }
    if (tid < 16) {   // constant-1 bias columns, both parities
        const int p = tid >> 3, b = tid & 7;
        u1h[p][b * S1H + 54] = (f16)1.0f;
        u2h[p][b * S2H + 100] = (f16)1.0f;
    }
    __syncthreads();

    // ---- hoisted per-parity LDS pointers ----
    const f16* u1bp[2] = { &u1h[0][b_me * S1H + q * 8], &u1h[1][b_me * S1H + q * 8] };
    const f16* u2bp[2] = { &u2h[0][b_me * S2H + q * 8], &u2h[1][b_me * S2H + q * 8] };
    f16* u1wp[2] = { &u1h[0][b_me * S1H], &u1h[1][b_me * S1H] };
    f16* u2wp[2] = { &u2h[0][b_me * S2H], &u2h[1][b_me * S2H] };

    // ---- superstep body (pr/pn become literals in the 2x-unrolled loop) ----
    auto body = [&](int s, int pr, int pn) __attribute__((always_inline)) {
        if (!grpB) {
            // ---------- x(s+1) prefetch (wave 0) ----------
            float4 xr;
            if (wv == 0 && lane < BB) {
                const int tn = (s + 1 < SEQ) ? s + 1 : SEQ - 1;
                xr = *reinterpret_cast<const float4*>(
                    x + ((size_t)tn * BATCH + bbase + lane) * 4);
            }
            // ---------- L1 gates(t=s): 7 tiles, 14 MFMA ----------
            const f16* ub = u1bp[pr];
            const v8h B0 = *reinterpret_cast<const v8h*>(ub);
            const v8h B1 = *reinterpret_cast<const v8h*>(ub + 32);
            v4f a[NTW];
#pragma unroll
            for (int t = 0; t < NTW; ++t) {
                a[t] = (v4f){0.f, 0.f, 0.f, 0.f};
                a[t] = MFMA(Af[t][0], B0, a[t]);
                a[t] = MFMA(Af[t][1], B1, a[t]);
            }
            // ---------- 4 lane-local unit updates ----------
#pragma unroll
            for (int s4 = 0; s4 < 4; ++s4) {
                const int hi = (s4 < 3) ? 4 + s4 : 3;
                const float m0 = hiHalf ? a[hi][0] : a[s4][0];
                const float m1 = hiHalf ? a[hi][1] : a[s4][1];
                const float m2 = hiHalf ? a[hi][2] : a[s4][2];
                const float m3 = hiHalf ? a[hi][3] : a[s4][3];
                const float A  = 1.0f + EXP2F(m0);
                const float F  = 1.0f + EXP2F(m1);
                const float Bv = 1.0f + EXP2F(m2);
                const float C  = 1.0f + EXP2F(m3);
                cst[s4] = RCPF(F) * cst[s4] + (Bv - 2.0f) * RCPF(A * Bv);
                const float D = 1.0f + EXP2F(cst[s4] * (2.0f * LOG2E));
                const float h1v = (D - 2.0f) * RCPF(C * D);
                if (vw_s[s4]) {
                    u1wp[pn][4 + u_s[s4]] = (f16)h1v;
                    u2wp[pr][u_s[s4]] = (f16)fmaxf(h1v, 0.0f);
                }
            }
            // ---------- out store for t=s-2 (wave 1) ----------
            if (wv == 1 && s >= 2 && lane < BB) {
                const float v = fcw[pn][0][lane] + fcw[pn][1][lane] + bfc;
                out[(size_t)(s - 2) * BATCH + bbase + lane] = v;
            }
            if (wv == 0 && lane < BB) {   // x(s+1) into next-parity u1
                f16 pk[4] = {(f16)xr.x, (f16)xr.y, (f16)xr.z, (f16)xr.w};
                *reinterpret_cast<uint2*>(&u1h[pn][lane * S1H]) = *reinterpret_cast<uint2*>(pk);
            }
        } else {
            // ---------- L2 gates(t=s-1): 7 tiles, 28 MFMA ----------
            const f16* ub = u2bp[pn];
            const v8h C0 = *reinterpret_cast<const v8h*>(ub);
            const v8h C1 = *reinterpret_cast<const v8h*>(ub + 32);
            const v8h C2 = *reinterpret_cast<const v8h*>(ub + 64);
            const v8h C3 = *reinterpret_cast<const v8h*>(ub + 96);
            v4f a[NTW];
#pragma unroll
            for (int t = 0; t < NTW; ++t) {
                a[t] = (v4f){0.f, 0.f, 0.f, 0.f};
                a[t] = MFMA(Af[t][0], C0, a[t]);
                a[t] = MFMA(Af[t][1], C1, a[t]);
                a[t] = MFMA(Af[t][2], C2, a[t]);
                a[t] = MFMA(Af[t][3], C3, a[t]);
            }
            // ---------- 4 lane-local unit updates + FC partial ----------
            float p = 0.0f;
#pragma unroll
            for (int s4 = 0; s4 < 4; ++s4) {
                const int hi = (s4 < 3) ? 4 + s4 : 3;
                const float m0 = hiHalf ? a[hi][0] : a[s4][0];
                const float m1 = hiHalf ? a[hi][1] : a[s4][1];
                const float m2 = hiHalf ? a[hi][2] : a[s4][2];
                const float m3 = hiHalf ? a[hi][3] : a[s4][3];
                const float A  = 1.0f + EXP2F(m0);
                const float F  = 1.0f + EXP2F(m1);
                const float Bv = 1.0f + EXP2F(m2);
                const float C  = 1.0f + EXP2F(m3);
                const float cn = RCPF(F) * cst[s4] + (Bv - 2.0f) * RCPF(A * Bv);
                const float D = 1.0f + EXP2F(cn * (2.0f * LOG2E));
                const float h2v = (D - 2.0f) * RCPF(C * D);
                if (s >= 1) {                       // t=s-1 valid
                    cst[s4] = cn;
                    if (vw_s[s4]) u2wp[pr][HID + u_s[s4]] = (f16)h2v;
                    p += fmaxf(h2v, 0.0f) * wfcv[s4];  // wfcv=0 on invalid/dup lanes
                }
            }
            p += __shfl_xor(p, 8);              // merge lo/hi tile halves (same batch)
            p += __shfl_xor(p, 16);             // merge quads
            p += __shfl_xor(p, 32);
            if (s >= 1 && lane < BB) fcw[pr][wv - 2][lane] = p;
        }
        __syncthreads();   // the ONE barrier per superstep (4 waves only)
    };

    // ---- pipelined supersteps, unrolled x2 (SEQ+2 = 514 is even) ----
#pragma unroll 1
    for (int s = 0; s < SEQ + 2; s += 2) {
        body(s, 0, 1);
        body(s + 1, 1, 0);
    }
}

extern "C" void kernel_launch(void* const* d_in, const int* in_sizes, int n_in,
                              void* d_out, int out_size, void* d_ws, size_t ws_size,
                              hipStream_t stream) {
    const float* X    = (const float*)d_in[0];
    const float* Wih1 = (const float*)d_in[1];
    const float* Whh1 = (const float*)d_in[2];
    const float* Bih1 = (const float*)d_in[3];
    const float* Bhh1 = (const float*)d_in[4];
    const float* Wih2 = (const float*)d_in[5];
    const float* Whh2 = (const float*)d_in[6];
    const float* Bih2 = (const float*)d_in[7];
    const float* Bhh2 = (const float*)d_in[8];
    const float* Wfc  = (const float*)d_in[9];
    const float* Bfc  = (const float*)d_in[10];
    float* out = (float*)d_out;

    lstm2_fused<<<dim3(NBLK), dim3(NTHR), 0, stream>>>(
        X, Wih1, Whh1, Bih1, Bhh1, Wih2, Whh2, Bih2, Bhh2, Wfc, Bfc, out);
}

// Round 4
// 466.468 us; speedup vs baseline: 1.0703x; 1.0703x over previous
//
#include <hip/hip_runtime.h>
#include <cstdint>

#define SEQ 512
#define BATCH 2048
#define HID 50
#define BB 8              // batches per block
#define NTHR 512          // 8 waves; EVERY wave does L1 and L2 for its tiles
#define NBLK (BATCH / BB) // 256 blocks -> 1 per CU, 2 waves per SIMD
#define NT 13             // gate-row tiles of 16 (200 -> 208, permuted rows)
#define S1H 80            // u1 stride halves: 40 dwords === 8 (mod 32)
#define S2H 144           // u2 stride halves: 72 dwords === 8 (mod 32)

typedef _Float16 f16;
typedef _Float16 v8h __attribute__((ext_vector_type(8)));
typedef float    v4f __attribute__((ext_vector_type(4)));

#if __has_builtin(__builtin_amdgcn_exp2f)
#define EXP2F(x) __builtin_amdgcn_exp2f(x)
#else
#define EXP2F(x) exp2f(x)
#endif
#define RCPF(x) __builtin_amdgcn_rcpf(x)
#define LOG2E 1.44269504f
#define MFMA(A,B,C) __builtin_amdgcn_mfma_f32_16x16x32_f16(A, B, C, 0, 0, 0)

// Row permutation (validated R5-R11): tile tt, in-tile row rho -> orig W row
// (rho%4)*50 + tt*4 + rho/4.  C layout (col=lane&15, row=(lane>>4)*4+reg)
// puts [i,f,g,o] of unit tt*4+q, batch col&7 in one lane's 4 C-regs.
// R3 structure: 8 waves; wave w owns tiles {w, w+8(if <13)} for BOTH layers.
// B cols = 8 batches x 2 copies; lane mb<8 reads accLo (tile w), mb>=8 reads
// accHi (tile w+8) -> 1 L1 update + 1 L2 update per lane (same as R0 totals,
// half the waves, intra-wave ILP across the two layer streams).
// All data deps cross the single per-superstep barrier (R0 parity discipline):
// L1(t=s) writes h1 -> u1[pn], relu(h1) -> u2[pr]; L2(t=s-1) reads u2[pn];
// FC partials -> fcw[pr]; out store t=s-2 reads fcw[pn]; x prefetch -> u1[pn].
// Biases ride constant-1.0 u-column (k=54 / k=100); gate rows pre-scaled
// (i,f,o: -log2e; g: +2log2e) so the update uses raw v_exp_f32.

__global__ __launch_bounds__(NTHR, 1) void lstm2_fused(
    const float* __restrict__ x,
    const float* __restrict__ w_ih1, const float* __restrict__ w_hh1,
    const float* __restrict__ b_ih1, const float* __restrict__ b_hh1,
    const float* __restrict__ w_ih2, const float* __restrict__ w_hh2,
    const float* __restrict__ b_ih2, const float* __restrict__ b_hh2,
    const float* __restrict__ w_fc, const float* __restrict__ b_fc,
    float* __restrict__ out)
{
    __shared__ __align__(16) f16 u1h[2][BB * S1H];
    __shared__ __align__(16) f16 u2h[2][BB * S2H];
    __shared__ float fcw[2][8][BB];

    const int tid  = threadIdx.x;
    const int wv   = tid >> 6;        // 0..7
    const int lane = tid & 63;
    const int mb   = lane & 15;       // A-row-in-tile | C col
    const int q    = lane >> 4;       // quad
    const int bbase = blockIdx.x * BB;

    const int  wa     = wv;                   // tile base
    const bool has2   = (wa < NT - 8);        // second tile wa+8 exists (wa<5)
    const bool hiHalf = (mb >= 8);
    const int  myt    = hiHalf ? (wa + 8) : wa;
    const int  u_me   = myt * 4 + q;
    const bool valid_upd = (myt < NT) && (u_me < HID);
    const int  b_me   = mb & 7;               // batch: B-col AND update identity

    const int   gidx = mb & 3;                // gate of this lane's A rows
    const float sc   = (gidx == 2) ? (2.0f * LOG2E) : (-LOG2E);

    // ---- weight-stationary A fragments for BOTH layers (scaled, bias col) ----
    v8h Af1[2][2];    // L1: [tile][ktile], K=64
    v8h Af2[2][4];    // L2: [tile][ktile], K=128
#pragma unroll
    for (int i = 0; i < 2; ++i) {
        const int tt = wa + 8 * i;
        const bool tv = (tt < NT);
        const int ru = tt * 4 + (mb >> 2);
        const bool rv = tv && (ru < HID);
        const int R = gidx * HID + ru;       // original gate-major W row
#pragma unroll
        for (int kt = 0; kt < 2; ++kt) {
            v8h f;
#pragma unroll
            for (int j = 0; j < 8; ++j) {
                const int kk = kt * 32 + q * 8 + j;
                float v = 0.0f;
                if (rv) {
                    if (kk < 4) v = w_ih1[R * 4 + kk];
                    else if (kk < 54) v = w_hh1[R * HID + (kk - 4)];
                    else if (kk == 54) v = b_ih1[R] + b_hh1[R];
                }
                f[j] = (f16)(v * sc);
            }
            Af1[i][kt] = f;
        }
#pragma unroll
        for (int kt = 0; kt < 4; ++kt) {
            v8h f;
#pragma unroll
            for (int j = 0; j < 8; ++j) {
                const int kk = kt * 32 + q * 8 + j;
                float v = 0.0f;
                if (rv) {
                    if (kk < HID) v = w_ih2[R * HID + kk];
                    else if (kk < 2 * HID) v = w_hh2[R * HID + (kk - HID)];
                    else if (kk == 100) v = b_ih2[R] + b_hh2[R];
                }
                f[j] = (f16)(v * sc);
            }
            Af2[i][kt] = f;
        }
    }
    const float wfc_me = valid_upd ? w_fc[u_me] : 0.0f;
    const float bfc = b_fc[0];
    float c1_me = 0.0f;   // L1 cell state for this lane's unit/batch
    float c2_me = 0.0f;   // L2 cell state

    // ---- LDS init ----
    for (int idx = tid; idx < 2 * BB * S1H; idx += NTHR) ((f16*)u1h)[idx] = (f16)0.0f;
    for (int idx = tid; idx < 2 * BB * S2H; idx += NTHR) ((f16*)u2h)[idx] = (f16)0.0f;
    if (tid < 128) ((float*)fcw)[tid] = 0.0f;
    __syncthreads();
    if (tid < BB) {   // x(0) -> u1 parity 0
        const float4 x0 = *reinterpret_cast<const float4*>(x + (size_t)(bbase + tid) * 4);
        f16 p[4] = {(f16)x0.x, (f16)x0.y, (f16)x0.z, (f16)x0.w};
        *reinterpret_cast<uint2*>(&u1h[0][tid * S1H]) = *reinterpret_cast<uint2*>(p);
    }
    if (tid < 16) {   // constant-1 bias columns, both parities
        const int p = tid >> 3, b = tid & 7;
        u1h[p][b * S1H + 54] = (f16)1.0f;
        u2h[p][b * S2H + 100] = (f16)1.0f;
    }
    __syncthreads();

    // ---- hoisted per-parity LDS pointers ----
    const f16* u1bp[2] = { &u1h[0][b_me * S1H + q * 8], &u1h[1][b_me * S1H + q * 8] };
    const f16* u2bp[2] = { &u2h[0][b_me * S2H + q * 8], &u2h[1][b_me * S2H + q * 8] };
    f16* u1wp[2] = { &u1h[0][b_me * S1H], &u1h[1][b_me * S1H] };
    f16* u2wp[2] = { &u2h[0][b_me * S2H], &u2h[1][b_me * S2H] };

    // ---- superstep body (pr/pn become literals in the 2x-unrolled loop) ----
    auto body = [&](int s, int pr, int pn) __attribute__((always_inline)) {
        // ---------- x(s+1) prefetch issue (wave 7, light) ----------
        float4 xr;
        if (wv == 7 && lane < BB) {
            const int tn = (s + 1 < SEQ) ? s + 1 : SEQ - 1;
            xr = *reinterpret_cast<const float4*>(
                x + ((size_t)tn * BATCH + bbase + lane) * 4);
        }

        // ---------- L1 gates(t=s) ----------
        const f16* u1r = u1bp[pr];
        const v8h B0 = *reinterpret_cast<const v8h*>(u1r);
        const v8h B1 = *reinterpret_cast<const v8h*>(u1r + 32);
        // ---------- L2 gates(t=s-1): reads issue early, independent stream ----------
        const f16* u2r = u2bp[pn];
        const v8h C0 = *reinterpret_cast<const v8h*>(u2r);
        const v8h C1 = *reinterpret_cast<const v8h*>(u2r + 32);
        const v8h C2 = *reinterpret_cast<const v8h*>(u2r + 64);
        const v8h C3 = *reinterpret_cast<const v8h*>(u2r + 96);

        v4f a0 = {0.f, 0.f, 0.f, 0.f}, a1 = a0;   // L1 acc (lo/hi tile)
        v4f d0 = {0.f, 0.f, 0.f, 0.f}, d1 = d0;   // L2 acc
        a0 = MFMA(Af1[0][0], B0, a0); a0 = MFMA(Af1[0][1], B1, a0);
        d0 = MFMA(Af2[0][0], C0, d0); d0 = MFMA(Af2[0][1], C1, d0);
        d0 = MFMA(Af2[0][2], C2, d0); d0 = MFMA(Af2[0][3], C3, d0);
        if (has2) {
            a1 = MFMA(Af1[1][0], B0, a1); a1 = MFMA(Af1[1][1], B1, a1);
            d1 = MFMA(Af2[1][0], C0, d1); d1 = MFMA(Af2[1][1], C1, d1);
            d1 = MFMA(Af2[1][2], C2, d1); d1 = MFMA(Af2[1][3], C3, d1);
        }

        // ---------- L1 lane-local unit update ----------
        {
            const float m0 = hiHalf ? a1[0] : a0[0];
            const float m1 = hiHalf ? a1[1] : a0[1];
            const float m2 = hiHalf ? a1[2] : a0[2];
            const float m3 = hiHalf ? a1[3] : a0[3];
            const float A  = 1.0f + EXP2F(m0);
            const float F  = 1.0f + EXP2F(m1);
            const float Bv = 1.0f + EXP2F(m2);
            const float C  = 1.0f + EXP2F(m3);
            c1_me = RCPF(F) * c1_me + (Bv - 2.0f) * RCPF(A * Bv);
            const float D = 1.0f + EXP2F(c1_me * (2.0f * LOG2E));
            const float h1v = (D - 2.0f) * RCPF(C * D);
            if (valid_upd) {
                u1wp[pn][4 + u_me] = (f16)h1v;
                u2wp[pr][u_me] = (f16)fmaxf(h1v, 0.0f);
            }
        }

        // ---------- L2 lane-local unit update + FC partial ----------
        {
            const float m0 = hiHalf ? d1[0] : d0[0];
            const float m1 = hiHalf ? d1[1] : d0[1];
            const float m2 = hiHalf ? d1[2] : d0[2];
            const float m3 = hiHalf ? d1[3] : d0[3];
            const float A  = 1.0f + EXP2F(m0);
            const float F  = 1.0f + EXP2F(m1);
            const float Bv = 1.0f + EXP2F(m2);
            const float C  = 1.0f + EXP2F(m3);
            const float cn = RCPF(F) * c2_me + (Bv - 2.0f) * RCPF(A * Bv);
            const float D = 1.0f + EXP2F(cn * (2.0f * LOG2E));
            const float h2v = (D - 2.0f) * RCPF(C * D);
            float p = 0.0f;
            if (s >= 1) {                       // t=s-1 valid
                c2_me = cn;
                if (valid_upd) u2wp[pr][HID + u_me] = (f16)h2v;
                p = fmaxf(h2v, 0.0f) * wfc_me;  // wfc_me=0 on invalid lanes
            }
            p += __shfl_xor(p, 8);              // merge lo/hi tile halves (same batch)
            p += __shfl_xor(p, 16);             // merge quads
            p += __shfl_xor(p, 32);
            if (s >= 1 && lane < BB) fcw[pr][wv][lane] = p;
        }

        // ---------- out store for t=s-2 (wave 6, light) ----------
        if (wv == 6 && s >= 2) {
            float v = ((const float*)fcw[pn])[lane];   // [wave=lane>>3][b=lane&7]
            v += __shfl_xor(v, 8);                     // sum the 8 wave-partials
            v += __shfl_xor(v, 16);
            v += __shfl_xor(v, 32);
            if (lane < BB) out[(size_t)(s - 2) * BATCH + bbase + lane] = v + bfc;
        }
        // ---------- x(s+1) write into next-parity u1 (wave 7) ----------
        if (wv == 7 && lane < BB) {
            f16 pk[4] = {(f16)xr.x, (f16)xr.y, (f16)xr.z, (f16)xr.w};
            *reinterpret_cast<uint2*>(&u1h[pn][lane * S1H]) = *reinterpret_cast<uint2*>(pk);
        }

        __syncthreads();   // the ONE barrier per superstep (8 waves)
    };

    // ---- pipelined supersteps, unrolled x2 (SEQ+2 = 514 is even) ----
#pragma unroll 1
    for (int s = 0; s < SEQ + 2; s += 2) {
        body(s, 0, 1);
        body(s + 1, 1, 0);
    }
}

extern "C" void kernel_launch(void* const* d_in, const int* in_sizes, int n_in,
                              void* d_out, int out_size, void* d_ws, size_t ws_size,
                              hipStream_t stream) {
    const float* X    = (const float*)d_in[0];
    const float* Wih1 = (const float*)d_in[1];
    const float* Whh1 = (const float*)d_in[2];
    const float* Bih1 = (const float*)d_in[3];
    const float* Bhh1 = (const float*)d_in[4];
    const float* Wih2 = (const float*)d_in[5];
    const float* Whh2 = (const float*)d_in[6];
    const float* Bih2 = (const float*)d_in[7];
    const float* Bhh2 = (const float*)d_in[8];
    const float* Wfc  = (const float*)d_in[9];
    const float* Bfc  = (const float*)d_in[10];
    float* out = (float*)d_out;

    lstm2_fused<<<dim3(NBLK), dim3(NTHR), 0, stream>>>(
        X, Wih1, Whh1, Bih1, Bhh1, Wih2, Whh2, Bih2, Bhh2, Wfc, Bfc, out);
}

// Round 5
// 461.858 us; speedup vs baseline: 1.0810x; 1.0100x over previous
//
#include <hip/hip_runtime.h>
#include <cstdint>

#define SEQ 512
#define BATCH 2048
#define HID 50
#define BB 8              // batches per block
#define NTHR 512          // 8 waves; EVERY wave does L1 and L2 for its tiles
#define NBLK (BATCH / BB) // 256 blocks -> 1 per CU, 2 waves per SIMD
#define NT 13             // gate-row tiles of 16 (200 -> 208, permuted rows)
#define S1H 80            // u1 stride halves: 40 dwords === 8 (mod 32)
#define S2H 144           // u2 stride halves: 72 dwords === 8 (mod 32)

typedef _Float16 f16;
typedef _Float16 v8h __attribute__((ext_vector_type(8)));
typedef float    v4f __attribute__((ext_vector_type(4)));

#if __has_builtin(__builtin_amdgcn_exp2f)
#define EXP2F(x) __builtin_amdgcn_exp2f(x)
#else
#define EXP2F(x) exp2f(x)
#endif
#define RCPF(x) __builtin_amdgcn_rcpf(x)
#define LOG2E 1.44269504f
#define MFMA(A,B,C) __builtin_amdgcn_mfma_f32_16x16x32_f16(A, B, C, 0, 0, 0)

// Row permutation (validated): tile tt, in-tile row rho -> orig W row
// (rho%4)*50 + tt*4 + rho/4.  C layout (col=lane&15, row=(lane>>4)*4+reg)
// puts [i,f,g,o] of unit tt*4+q, batch col&7 in one lane's 4 C-regs.
// R4 structure = R3 (8 waves, wave w owns tiles {w, w+8} for BOTH layers)
// + ZERO global memory ops inside the superstep loop:
//   - x preloaded to LDS (f16) in prologue (xl[t][b*4+j], t=tid exact fit)
//   - wave 7 stages x(s+1) via LDS->LDS copy (lgkmcnt only, no vmcnt)
//   - wave 6 writes out values to LDS outb; epilogue flushes to global
// => the compiler's mandatory `s_waitcnt vmcnt(0)` before each s_barrier is
// trivially satisfied; the per-superstep HBM-latency drain (the ~2000cy floor
// invariant across R0/R2/R3 wave configs) is removed.
// All data deps cross the single per-superstep barrier (parity discipline):
// L1(t=s) writes h1 -> u1[pn], relu(h1) -> u2[pr]; L2(t=s-1) reads u2[pn];
// FC partials -> fcw[pr]; outb store t=s-2 reads fcw[pn]; x copy -> u1[pn].
// Biases ride constant-1.0 u-column (k=54 / k=100); gate rows pre-scaled
// (i,f,o: -log2e; g: +2log2e) so the update uses raw v_exp_f32.

__global__ __launch_bounds__(NTHR, 1) void lstm2_fused(
    const float* __restrict__ x,
    const float* __restrict__ w_ih1, const float* __restrict__ w_hh1,
    const float* __restrict__ b_ih1, const float* __restrict__ b_hh1,
    const float* __restrict__ w_ih2, const float* __restrict__ w_hh2,
    const float* __restrict__ b_ih2, const float* __restrict__ b_hh2,
    const float* __restrict__ w_fc, const float* __restrict__ b_fc,
    float* __restrict__ out)
{
    __shared__ __align__(16) f16 u1h[2][BB * S1H];
    __shared__ __align__(16) f16 u2h[2][BB * S2H];
    __shared__ float fcw[2][8][BB];
    __shared__ __align__(16) f16 xl[SEQ][BB * 4];     // 32 KB: whole x slice
    __shared__ __align__(16) float outb[SEQ][BB];     // 16 KB: out accumulator

    const int tid  = threadIdx.x;
    const int wv   = tid >> 6;        // 0..7
    const int lane = tid & 63;
    const int mb   = lane & 15;       // A-row-in-tile | C col
    const int q    = lane >> 4;       // quad
    const int bbase = blockIdx.x * BB;

    const int  wa     = wv;                   // tile base
    const bool has2   = (wa < NT - 8);        // second tile wa+8 exists (wa<5)
    const bool hiHalf = (mb >= 8);
    const int  myt    = hiHalf ? (wa + 8) : wa;
    const int  u_me   = myt * 4 + q;
    const bool valid_upd = (myt < NT) && (u_me < HID);
    const int  b_me   = mb & 7;               // batch: B-col AND update identity

    const int   gidx = mb & 3;                // gate of this lane's A rows
    const float sc   = (gidx == 2) ? (2.0f * LOG2E) : (-LOG2E);

    // ---- weight-stationary A fragments for BOTH layers (scaled, bias col) ----
    v8h Af1[2][2];    // L1: [tile][ktile], K=64
    v8h Af2[2][4];    // L2: [tile][ktile], K=128
#pragma unroll
    for (int i = 0; i < 2; ++i) {
        const int tt = wa + 8 * i;
        const bool tv = (tt < NT);
        const int ru = tt * 4 + (mb >> 2);
        const bool rv = tv && (ru < HID);
        const int R = gidx * HID + ru;       // original gate-major W row
#pragma unroll
        for (int kt = 0; kt < 2; ++kt) {
            v8h f;
#pragma unroll
            for (int j = 0; j < 8; ++j) {
                const int kk = kt * 32 + q * 8 + j;
                float v = 0.0f;
                if (rv) {
                    if (kk < 4) v = w_ih1[R * 4 + kk];
                    else if (kk < 54) v = w_hh1[R * HID + (kk - 4)];
                    else if (kk == 54) v = b_ih1[R] + b_hh1[R];
                }
                f[j] = (f16)(v * sc);
            }
            Af1[i][kt] = f;
        }
#pragma unroll
        for (int kt = 0; kt < 4; ++kt) {
            v8h f;
#pragma unroll
            for (int j = 0; j < 8; ++j) {
                const int kk = kt * 32 + q * 8 + j;
                float v = 0.0f;
                if (rv) {
                    if (kk < HID) v = w_ih2[R * HID + kk];
                    else if (kk < 2 * HID) v = w_hh2[R * HID + (kk - HID)];
                    else if (kk == 100) v = b_ih2[R] + b_hh2[R];
                }
                f[j] = (f16)(v * sc);
            }
            Af2[i][kt] = f;
        }
    }
    const float wfc_me = valid_upd ? w_fc[u_me] : 0.0f;
    const float bfc = b_fc[0];
    float c1_me = 0.0f;   // L1 cell state for this lane's unit/batch
    float c2_me = 0.0f;   // L2 cell state

    // ---- LDS init ----
    for (int idx = tid; idx < 2 * BB * S1H; idx += NTHR) ((f16*)u1h)[idx] = (f16)0.0f;
    for (int idx = tid; idx < 2 * BB * S2H; idx += NTHR) ((f16*)u2h)[idx] = (f16)0.0f;
    if (tid < 128) ((float*)fcw)[tid] = 0.0f;

    // ---- prologue: preload whole x slice -> LDS as f16 (t = tid, exact fit) ----
    {
        const int t = tid;   // NTHR == SEQ == 512
        const float* xrow = x + ((size_t)t * BATCH + bbase) * 4;
#pragma unroll
        for (int b = 0; b < BB; ++b) {
            const float4 v = *reinterpret_cast<const float4*>(xrow + b * 4);
            f16 p[4] = {(f16)v.x, (f16)v.y, (f16)v.z, (f16)v.w};
            *reinterpret_cast<uint2*>(&xl[t][b * 4]) = *reinterpret_cast<uint2*>(p);
        }
    }
    __syncthreads();
    if (tid < BB) {   // x(0) -> u1 parity 0 (from LDS copy)
        *reinterpret_cast<uint2*>(&u1h[0][tid * S1H]) =
            *reinterpret_cast<const uint2*>(&xl[0][tid * 4]);
    }
    if (tid < 16) {   // constant-1 bias columns, both parities
        const int p = tid >> 3, b = tid & 7;
        u1h[p][b * S1H + 54] = (f16)1.0f;
        u2h[p][b * S2H + 100] = (f16)1.0f;
    }
    __syncthreads();

    // ---- hoisted per-parity LDS pointers ----
    const f16* u1bp[2] = { &u1h[0][b_me * S1H + q * 8], &u1h[1][b_me * S1H + q * 8] };
    const f16* u2bp[2] = { &u2h[0][b_me * S2H + q * 8], &u2h[1][b_me * S2H + q * 8] };
    f16* u1wp[2] = { &u1h[0][b_me * S1H], &u1h[1][b_me * S1H] };
    f16* u2wp[2] = { &u2h[0][b_me * S2H], &u2h[1][b_me * S2H] };

    // ---- superstep body (pr/pn become literals in the 2x-unrolled loop) ----
    auto body = [&](int s, int pr, int pn) __attribute__((always_inline)) {
        // ---------- x(s+1) staging: LDS -> LDS, no vmcnt (wave 7, light) ----------
        if (wv == 7 && lane < BB) {
            const int tn = (s + 1 < SEQ) ? s + 1 : SEQ - 1;
            *reinterpret_cast<uint2*>(&u1h[pn][lane * S1H]) =
                *reinterpret_cast<const uint2*>(&xl[tn][lane * 4]);
        }

        // ---------- L1 gates(t=s) ----------
        const f16* u1r = u1bp[pr];
        const v8h B0 = *reinterpret_cast<const v8h*>(u1r);
        const v8h B1 = *reinterpret_cast<const v8h*>(u1r + 32);
        // ---------- L2 gates(t=s-1): reads issue early, independent stream ----------
        const f16* u2r = u2bp[pn];
        const v8h C0 = *reinterpret_cast<const v8h*>(u2r);
        const v8h C1 = *reinterpret_cast<const v8h*>(u2r + 32);
        const v8h C2 = *reinterpret_cast<const v8h*>(u2r + 64);
        const v8h C3 = *reinterpret_cast<const v8h*>(u2r + 96);

        v4f a0 = {0.f, 0.f, 0.f, 0.f}, a1 = a0;   // L1 acc (lo/hi tile)
        v4f d0 = {0.f, 0.f, 0.f, 0.f}, d1 = d0;   // L2 acc
        a0 = MFMA(Af1[0][0], B0, a0); a0 = MFMA(Af1[0][1], B1, a0);
        d0 = MFMA(Af2[0][0], C0, d0); d0 = MFMA(Af2[0][1], C1, d0);
        d0 = MFMA(Af2[0][2], C2, d0); d0 = MFMA(Af2[0][3], C3, d0);
        if (has2) {
            a1 = MFMA(Af1[1][0], B0, a1); a1 = MFMA(Af1[1][1], B1, a1);
            d1 = MFMA(Af2[1][0], C0, d1); d1 = MFMA(Af2[1][1], C1, d1);
            d1 = MFMA(Af2[1][2], C2, d1); d1 = MFMA(Af2[1][3], C3, d1);
        }

        // ---------- L1 lane-local unit update ----------
        {
            const float m0 = hiHalf ? a1[0] : a0[0];
            const float m1 = hiHalf ? a1[1] : a0[1];
            const float m2 = hiHalf ? a1[2] : a0[2];
            const float m3 = hiHalf ? a1[3] : a0[3];
            const float A  = 1.0f + EXP2F(m0);
            const float F  = 1.0f + EXP2F(m1);
            const float Bv = 1.0f + EXP2F(m2);
            const float C  = 1.0f + EXP2F(m3);
            c1_me = RCPF(F) * c1_me + (Bv - 2.0f) * RCPF(A * Bv);
            const float D = 1.0f + EXP2F(c1_me * (2.0f * LOG2E));
            const float h1v = (D - 2.0f) * RCPF(C * D);
            if (valid_upd) {
                u1wp[pn][4 + u_me] = (f16)h1v;
                u2wp[pr][u_me] = (f16)fmaxf(h1v, 0.0f);
            }
        }

        // ---------- L2 lane-local unit update + FC partial ----------
        {
            const float m0 = hiHalf ? d1[0] : d0[0];
            const float m1 = hiHalf ? d1[1] : d0[1];
            const float m2 = hiHalf ? d1[2] : d0[2];
            const float m3 = hiHalf ? d1[3] : d0[3];
            const float A  = 1.0f + EXP2F(m0);
            const float F  = 1.0f + EXP2F(m1);
            const float Bv = 1.0f + EXP2F(m2);
            const float C  = 1.0f + EXP2F(m3);
            const float cn = RCPF(F) * c2_me + (Bv - 2.0f) * RCPF(A * Bv);
            const float D = 1.0f + EXP2F(cn * (2.0f * LOG2E));
            const float h2v = (D - 2.0f) * RCPF(C * D);
            float p = 0.0f;
            if (s >= 1) {                       // t=s-1 valid
                c2_me = cn;
                if (valid_upd) u2wp[pr][HID + u_me] = (f16)h2v;
                p = fmaxf(h2v, 0.0f) * wfc_me;  // wfc_me=0 on invalid lanes
            }
            p += __shfl_xor(p, 8);              // merge lo/hi tile halves (same batch)
            p += __shfl_xor(p, 16);             // merge quads
            p += __shfl_xor(p, 32);
            if (s >= 1 && lane < BB) fcw[pr][wv][lane] = p;
        }

        // ---------- out value t=s-2 -> LDS accumulator (wave 6, light) ----------
        if (wv == 6 && s >= 2) {
            float v = ((const float*)fcw[pn])[lane];   // [wave=lane>>3][b=lane&7]
            v += __shfl_xor(v, 8);                     // sum the 8 wave-partials
            v += __shfl_xor(v, 16);
            v += __shfl_xor(v, 32);
            if (lane < BB) outb[s - 2][lane] = v + bfc;
        }

        __syncthreads();   // ONE barrier; drains LDS only (no VMEM in flight)
    };

    // ---- pipelined supersteps, unrolled x2 (SEQ+2 = 514 is even) ----
#pragma unroll 1
    for (int s = 0; s < SEQ + 2; s += 2) {
        body(s, 0, 1);
        body(s + 1, 1, 0);
    }

    // ---- epilogue: flush outb -> global (t = tid, 8 floats each) ----
    {
        const int t = tid;   // NTHR == SEQ
        float* orow = out + (size_t)t * BATCH + bbase;
        const float* src = &outb[t][0];
        *reinterpret_cast<float4*>(orow)     = *reinterpret_cast<const float4*>(src);
        *reinterpret_cast<float4*>(orow + 4) = *reinterpret_cast<const float4*>(src + 4);
    }
}

extern "C" void kernel_launch(void* const* d_in, const int* in_sizes, int n_in,
                              void* d_out, int out_size, void* d_ws, size_t ws_size,
                              hipStream_t stream) {
    const float* X    = (const float*)d_in[0];
    const float* Wih1 = (const float*)d_in[1];
    const float* Whh1 = (const float*)d_in[2];
    const float* Bih1 = (const float*)d_in[3];
    const float* Bhh1 = (const float*)d_in[4];
    const float* Wih2 = (const float*)d_in[5];
    const float* Whh2 = (const float*)d_in[6];
    const float* Bih2 = (const float*)d_in[7];
    const float* Bhh2 = (const float*)d_in[8];
    const float* Wfc  = (const float*)d_in[9];
    const float* Bfc  = (const float*)d_in[10];
    float* out = (float*)d_out;

    lstm2_fused<<<dim3(NBLK), dim3(NTHR), 0, stream>>>(
        X, Wih1, Whh1, Bih1, Bhh1, Wih2, Whh2, Bih2, Bhh2, Wfc, Bfc, out);
}

// Round 6
// 338.862 us; speedup vs baseline: 1.4733x; 1.3630x over previous
//
#include <hip/hip_runtime.h>
#include <cstdint>

#define SEQ 512
#define BATCH 2048
#define HID 50
#define BB 8              // batches per block
#define NTHR 1024         // 16 waves: 0-7 = L1 group, 8-15 = L2 group (R0 base)
#define NBLK (BATCH / BB) // 256 blocks -> 1 per CU
#define NT 13             // gate-row tiles of 16 (200 -> 208, permuted rows)
#define S1H 80            // u1 stride halves: 40 dwords === 8 (mod 32)
#define S2H 144           // u2 stride halves: 72 dwords === 8 (mod 32)

typedef _Float16 f16;
typedef _Float16 v8h __attribute__((ext_vector_type(8)));
typedef float    v4f __attribute__((ext_vector_type(4)));

#if __has_builtin(__builtin_amdgcn_exp2f)
#define EXP2F(x) __builtin_amdgcn_exp2f(x)
#else
#define EXP2F(x) exp2f(x)
#endif
#define RCPF(x) __builtin_amdgcn_rcpf(x)
#define LOG2E 1.44269504f
#define MFMA(A,B,C) __builtin_amdgcn_mfma_f32_16x16x32_f16(A, B, C, 0, 0, 0)

// R6 = R0 (16-wave, best measured 419us) + issue cuts:
//  - bias rides MFMA C-in (bias0/bias1 v4f, per-(q,reg)): no acc zero-init
//    movs, no 1.0-column, no k=54/k=100 bias loads in A.
//  - merged-rcp update: c' = (c*A*Bv + (Bv-2)*F)*rcp(F*A*Bv)  [3 rcp -> 2]
//  - FC rebalance: L2 waves store RAW p (no shfls, shorter laggard tail);
//    light L1 wave 6 reduces 8x64 partials -> 8 outputs.
//  - x preloaded to LDS (xl), out buffered in LDS (outb): zero global ops
//    in the superstep loop (R5-proven).
// Row permutation (validated): tile tt, in-tile row rho -> orig W row
// (rho%4)*50 + tt*4 + rho/4.  C layout (col=lane&15, row=(lane>>4)*4+reg):
// lane holds gates [i,f,g,o] (reg 0..3) of unit tt*4+q, batch col&7.
// Parity discipline (R0-validated): L1(t=s) reads u1[pr], writes h1->u1[pn],
// relu(h1)->u2[pr]; L2(t=s-1) reads u2[pn]; fcw[pr] written, fcw[pn] read.
// Gate rows pre-scaled (i,f,o: -log2e; g: +2log2e) -> raw v_exp_f32.

__global__ __launch_bounds__(NTHR, 1) void lstm2_fused(
    const float* __restrict__ x,
    const float* __restrict__ w_ih1, const float* __restrict__ w_hh1,
    const float* __restrict__ b_ih1, const float* __restrict__ b_hh1,
    const float* __restrict__ w_ih2, const float* __restrict__ w_hh2,
    const float* __restrict__ b_ih2, const float* __restrict__ b_hh2,
    const float* __restrict__ w_fc, const float* __restrict__ b_fc,
    float* __restrict__ out)
{
    __shared__ __align__(16) f16 u1h[2][BB * S1H];        // 2560 B
    __shared__ __align__(16) f16 u2h[2][BB * S2H];        // 4608 B
    __shared__ float fcw[2][8][64];                       // 4096 B raw FC partials
    __shared__ __align__(16) f16 xl[SEQ][BB * 4];         // 32 KB: whole x slice
    __shared__ __align__(16) float outb[SEQ][BB];         // 16 KB: out buffer

    const int tid  = threadIdx.x;
    const int wv   = tid >> 6;        // 0..15
    const int lane = tid & 63;
    const int mb   = lane & 15;       // A-row-in-tile | C col
    const int q    = lane >> 4;       // quad
    const int bbase = blockIdx.x * BB;

    const bool grpB = (wv >= 8);              // waves 8-15: L2
    const int  wa   = grpB ? (15 - wv) : wv;  // 0..7

    const bool hiHalf = (mb >= 8);
    const int  myt    = hiHalf ? (wa + 8) : wa;
    const int  u_me   = myt * 4 + q;
    const bool valid_upd = (myt < NT) && (u_me < HID);
    const int  b_me   = mb & 7;       // batch: B-col AND update identity

    const int   gidx = mb & 3;        // gate of this lane's A rows
    const float sc   = (gidx == 2) ? (2.0f * LOG2E) : (-LOG2E);

    // ---- weight-stationary A fragments (scaled, NO bias column) ----
    v8h Af[2][4];                     // [tile][ktile]; L1 uses kt 0..1, L2 kt 0..3
#pragma unroll
    for (int i = 0; i < 2; ++i) {
        const int tt = wa + 8 * i;
        const bool tv = (tt < NT);
        const int ru = tt * 4 + (mb >> 2);
        const bool rv = tv && (ru < HID);
        const int R = gidx * HID + ru;       // original gate-major W row
        if (!grpB) {
#pragma unroll
            for (int kt = 0; kt < 2; ++kt) {
                v8h f;
#pragma unroll
                for (int j = 0; j < 8; ++j) {
                    const int kk = kt * 32 + q * 8 + j;
                    float v = 0.0f;
                    if (rv) {
                        if (kk < 4) v = w_ih1[R * 4 + kk];
                        else if (kk < 54) v = w_hh1[R * HID + (kk - 4)];
                    }
                    f[j] = (f16)(v * sc);
                }
                Af[i][kt] = f;
            }
        } else {
#pragma unroll
            for (int kt = 0; kt < 4; ++kt) {
                v8h f;
#pragma unroll
                for (int j = 0; j < 8; ++j) {
                    const int kk = kt * 32 + q * 8 + j;
                    float v = 0.0f;
                    if (rv) {
                        if (kk < HID) v = w_ih2[R * HID + kk];
                        else if (kk < 2 * HID) v = w_hh2[R * HID + (kk - HID)];
                    }
                    f[j] = (f16)(v * sc);
                }
                Af[i][kt] = f;
            }
        }
    }

    // ---- bias accumulators (C-in): reg r = gate r, unit = tile*4+q ----
    v4f bias0 = {0.f, 0.f, 0.f, 0.f}, bias1 = {0.f, 0.f, 0.f, 0.f};
#pragma unroll
    for (int r = 0; r < 4; ++r) {
        const float scr = (r == 2) ? (2.0f * LOG2E) : (-LOG2E);
        const int u0 = wa * 4 + q;
        const int u1t = (wa + 8) * 4 + q;
        const float* bi = grpB ? b_ih2 : b_ih1;
        const float* bh = grpB ? b_hh2 : b_hh1;
        if (u0 < HID) bias0[r] = (bi[r * HID + u0] + bh[r * HID + u0]) * scr;
        if ((wa + 8) < NT && u1t < HID)
            bias1[r] = (bi[r * HID + u1t] + bh[r * HID + u1t]) * scr;
    }
    const float wfc_me = (grpB && valid_upd) ? w_fc[u_me] : 0.0f;
    const float bfc = b_fc[0];
    float c_me = 0.0f;                // L1 cell (waves 0-7) / L2 cell (waves 8-15)

    // ---- LDS init + x preload ----
    for (int idx = tid; idx < 2 * BB * S1H; idx += NTHR) ((f16*)u1h)[idx] = (f16)0.0f;
    for (int idx = tid; idx < 2 * BB * S2H; idx += NTHR) ((f16*)u2h)[idx] = (f16)0.0f;
    ((float*)fcw)[tid] = 0.0f;        // 2*8*64 = 1024 == NTHR
    for (int i = tid; i < SEQ * BB; i += NTHR) {   // 4 iters, coalesced
        const int t = i >> 3, b = i & 7;
        const float4 v = *reinterpret_cast<const float4*>(
            x + ((size_t)t * BATCH + bbase + b) * 4);
        f16 p[4] = {(f16)v.x, (f16)v.y, (f16)v.z, (f16)v.w};
        *reinterpret_cast<uint2*>(&xl[t][b * 4]) = *reinterpret_cast<uint2*>(p);
    }
    __syncthreads();
    if (tid < BB) {   // x(0) -> u1 parity 0
        *reinterpret_cast<uint2*>(&u1h[0][tid * S1H]) =
            *reinterpret_cast<const uint2*>(&xl[0][tid * 4]);
    }
    __syncthreads();

    // ---- hoisted per-parity LDS pointers ----
    const f16* u1rp[2] = {u1h[0] + b_me * S1H, u1h[1] + b_me * S1H};
    const f16* u2rp[2] = {u2h[0] + b_me * S2H, u2h[1] + b_me * S2H};
    f16* u1wp[2] = {u1h[0] + b_me * S1H, u1h[1] + b_me * S1H};
    f16* u2wp[2] = {u2h[0] + b_me * S2H, u2h[1] + b_me * S2H};

    // ---- superstep body (pr/pn become literals in the 2x-unrolled loop) ----
    auto body = [&](int s, int pr, int pn) __attribute__((always_inline)) {
        if (!grpB) {
            // ---------- L1 gates(t=s) ----------
            const f16* u1r = u1rp[pr];
            const v8h B0 = *reinterpret_cast<const v8h*>(&u1r[q * 8]);
            const v8h B1 = *reinterpret_cast<const v8h*>(&u1r[32 + q * 8]);
            v4f a0 = bias0, a1 = bias1;
            a0 = MFMA(Af[0][0], B0, a0);
            a0 = MFMA(Af[0][1], B1, a0);
            if (wa < NT - 8) {
                a1 = MFMA(Af[1][0], B0, a1);
                a1 = MFMA(Af[1][1], B1, a1);
            }
            const float m0 = hiHalf ? a1[0] : a0[0];
            const float m1 = hiHalf ? a1[1] : a0[1];
            const float m2 = hiHalf ? a1[2] : a0[2];
            const float m3 = hiHalf ? a1[3] : a0[3];
            const float A  = 1.0f + EXP2F(m0);
            const float F  = 1.0f + EXP2F(m1);
            const float Bv = 1.0f + EXP2F(m2);
            const float C  = 1.0f + EXP2F(m3);
            const float AB = A * Bv;
            c_me = (c_me * AB + (Bv - 2.0f) * F) * RCPF(F * AB);
            const float D = 1.0f + EXP2F(c_me * (2.0f * LOG2E));
            const float h1v = (D - 2.0f) * RCPF(C * D);
            if (valid_upd) {
                u1wp[pn][4 + u_me] = (f16)h1v;
                u2wp[pr][u_me] = (f16)fmaxf(h1v, 0.0f);
            }
            // ---------- out reduce+store for t=s-2 (light wave 6) ----------
            if (wv == 6 && s >= 2) {
                float v = 0.0f;
#pragma unroll
                for (int k2 = 0; k2 < 8; ++k2) v += fcw[pn][k2][lane];
                v += __shfl_xor(v, 8);     // merge lo/hi tile halves (same batch)
                v += __shfl_xor(v, 16);    // merge quads
                v += __shfl_xor(v, 32);
                if (lane < BB) outb[s - 2][lane] = v + bfc;
            }
        } else {
            // ---------- x(s+1) staging: LDS -> LDS (light wave 8) ----------
            if (wv == 8 && lane < BB) {
                const int tn = (s + 1 < SEQ) ? s + 1 : SEQ - 1;
                *reinterpret_cast<uint2*>(&u1h[pn][lane * S1H]) =
                    *reinterpret_cast<const uint2*>(&xl[tn][lane * 4]);
            }
            // ---------- L2 gates(t=s-1) ----------
            const f16* u2r = u2rp[pn];
            const v8h C0 = *reinterpret_cast<const v8h*>(&u2r[q * 8]);
            const v8h C1 = *reinterpret_cast<const v8h*>(&u2r[32 + q * 8]);
            const v8h C2 = *reinterpret_cast<const v8h*>(&u2r[64 + q * 8]);
            const v8h C3 = *reinterpret_cast<const v8h*>(&u2r[96 + q * 8]);
            v4f a0 = bias0, a1 = bias1;
            a0 = MFMA(Af[0][0], C0, a0);
            a0 = MFMA(Af[0][1], C1, a0);
            a0 = MFMA(Af[0][2], C2, a0);
            a0 = MFMA(Af[0][3], C3, a0);
            if (wa < NT - 8) {
                a1 = MFMA(Af[1][0], C0, a1);
                a1 = MFMA(Af[1][1], C1, a1);
                a1 = MFMA(Af[1][2], C2, a1);
                a1 = MFMA(Af[1][3], C3, a1);
            }
            const float m0 = hiHalf ? a1[0] : a0[0];
            const float m1 = hiHalf ? a1[1] : a0[1];
            const float m2 = hiHalf ? a1[2] : a0[2];
            const float m3 = hiHalf ? a1[3] : a0[3];
            const float A  = 1.0f + EXP2F(m0);
            const float F  = 1.0f + EXP2F(m1);
            const float Bv = 1.0f + EXP2F(m2);
            const float C  = 1.0f + EXP2F(m3);
            const float AB = A * Bv;
            const float cn = (c_me * AB + (Bv - 2.0f) * F) * RCPF(F * AB);
            const float D = 1.0f + EXP2F(cn * (2.0f * LOG2E));
            const float h2v = (D - 2.0f) * RCPF(C * D);
            float p = 0.0f;
            if (s >= 1) {                       // t=s-1 valid
                c_me = cn;
                if (valid_upd) u2wp[pr][HID + u_me] = (f16)h2v;
                p = fmaxf(h2v, 0.0f) * wfc_me;  // wfc_me=0 on invalid lanes
            }
            fcw[pr][wv - 8][lane] = p;          // RAW partial, no shfl tail
        }
        __syncthreads();   // the ONE barrier per superstep
    };

    // ---- pipelined supersteps, unrolled x2 (SEQ+2 = 514 is even) ----
#pragma unroll 1
    for (int s = 0; s < SEQ + 2; s += 2) {
        body(s, 0, 1);
        body(s + 1, 1, 0);
    }

    // ---- epilogue: flush outb -> global ----
    {
        const int i = tid;                 // SEQ*2 == 1024 == NTHR
        const int t = i >> 1, hb = (i & 1) * 4;
        *reinterpret_cast<float4*>(out + (size_t)t * BATCH + bbase + hb) =
            *reinterpret_cast<const float4*>(&outb[t][hb]);
    }
}

extern "C" void kernel_launch(void* const* d_in, const int* in_sizes, int n_in,
                              void* d_out, int out_size, void* d_ws, size_t ws_size,
                              hipStream_t stream) {
    const float* X    = (const float*)d_in[0];
    const float* Wih1 = (const float*)d_in[1];
    const float* Whh1 = (const float*)d_in[2];
    const float* Bih1 = (const float*)d_in[3];
    const float* Bhh1 = (const float*)d_in[4];
    const float* Wih2 = (const float*)d_in[5];
    const float* Whh2 = (const float*)d_in[6];
    const float* Bih2 = (const float*)d_in[7];
    const float* Bhh2 = (const float*)d_in[8];
    const float* Wfc  = (const float*)d_in[9];
    const float* Bfc  = (const float*)d_in[10];
    float* out = (float*)d_out;

    lstm2_fused<<<dim3(NBLK), dim3(NTHR), 0, stream>>>(
        X, Wih1, Whh1, Bih1, Bhh1, Wih2, Whh2, Bih2, Bhh2, Wfc, Bfc, out);
}

// Round 7
// 332.697 us; speedup vs baseline: 1.5006x; 1.0185x over previous
//
#include <hip/hip_runtime.h>
#include <cstdint>

#define SEQ 512
#define BATCH 2048
#define HID 50
#define BB 8              // batches per block
#define NTHR 1024         // 16 waves: 0-7 = L1 group, 8-15 = L2 group (R0 base)
#define NBLK (BATCH / BB) // 256 blocks -> 1 per CU
#define NT 13             // gate-row tiles of 16 (200 -> 208, permuted rows)
#define S1H 80            // u1 stride halves: 40 dwords === 8 (mod 32)
#define S2H 144           // u2 stride halves: 72 dwords === 8 (mod 32)

typedef _Float16 f16;
typedef _Float16 v8h __attribute__((ext_vector_type(8)));
typedef float    v4f __attribute__((ext_vector_type(4)));

#if __has_builtin(__builtin_amdgcn_exp2f)
#define EXP2F(x) __builtin_amdgcn_exp2f(x)
#else
#define EXP2F(x) exp2f(x)
#endif
#define RCPF(x) __builtin_amdgcn_rcpf(x)
#define LOG2E 1.44269504f
#define MFMA(A,B,C) __builtin_amdgcn_mfma_f32_16x16x32_f16(A, B, C, 0, 0, 0)

// R7 = R6 (338.9us bench / 298.6 best dispatch) + skew cuts:
//  - static s_setprio(1) on heavy (2-tile) waves: barrier laggards get issue
//    preference over light/service waves (T5 mechanism: role diversity).
//  - single-tile waves (wa>=5) skip the hiHalf accumulator selects (their hi
//    lanes are invalid; m = a0 unconditionally under a wave-uniform branch).
// Carried from R6: bias rides MFMA C-in; merged-rcp update (2 rcp); L2 waves
// store RAW fc partials (light wave 6 reduces); x in LDS (xl), out in LDS
// (outb) -> zero global ops in the superstep loop.
// Row permutation (validated): tile tt, in-tile row rho -> orig W row
// (rho%4)*50 + tt*4 + rho/4.  C layout (col=lane&15, row=(lane>>4)*4+reg):
// lane holds gates [i,f,g,o] (reg 0..3) of unit tt*4+q, batch col&7.
// Parity discipline (R0-validated): L1(t=s) reads u1[pr], writes h1->u1[pn],
// relu(h1)->u2[pr]; L2(t=s-1) reads u2[pn]; fcw[pr] written, fcw[pn] read.
// Gate rows pre-scaled (i,f,o: -log2e; g: +2log2e) -> raw v_exp_f32.

__global__ __launch_bounds__(NTHR, 1) void lstm2_fused(
    const float* __restrict__ x,
    const float* __restrict__ w_ih1, const float* __restrict__ w_hh1,
    const float* __restrict__ b_ih1, const float* __restrict__ b_hh1,
    const float* __restrict__ w_ih2, const float* __restrict__ w_hh2,
    const float* __restrict__ b_ih2, const float* __restrict__ b_hh2,
    const float* __restrict__ w_fc, const float* __restrict__ b_fc,
    float* __restrict__ out)
{
    __shared__ __align__(16) f16 u1h[2][BB * S1H];        // 2560 B
    __shared__ __align__(16) f16 u2h[2][BB * S2H];        // 4608 B
    __shared__ float fcw[2][8][64];                       // 4096 B raw FC partials
    __shared__ __align__(16) f16 xl[SEQ][BB * 4];         // 32 KB: whole x slice
    __shared__ __align__(16) float outb[SEQ][BB];         // 16 KB: out buffer

    const int tid  = threadIdx.x;
    const int wv   = tid >> 6;        // 0..15
    const int lane = tid & 63;
    const int mb   = lane & 15;       // A-row-in-tile | C col
    const int q    = lane >> 4;       // quad
    const int bbase = blockIdx.x * BB;

    const bool grpB = (wv >= 8);              // waves 8-15: L2
    const int  wa   = grpB ? (15 - wv) : wv;  // 0..7
    const bool heavy = (wa < NT - 8);         // 2-tile wave

    const bool hiHalf = (mb >= 8);
    const int  myt    = hiHalf ? (wa + 8) : wa;
    const int  u_me   = myt * 4 + q;
    const bool valid_upd = (myt < NT) && (u_me < HID);
    const int  b_me   = mb & 7;       // batch: B-col AND update identity

    const int   gidx = mb & 3;        // gate of this lane's A rows
    const float sc   = (gidx == 2) ? (2.0f * LOG2E) : (-LOG2E);

    // ---- weight-stationary A fragments (scaled, NO bias column) ----
    v8h Af[2][4];                     // [tile][ktile]; L1 uses kt 0..1, L2 kt 0..3
#pragma unroll
    for (int i = 0; i < 2; ++i) {
        const int tt = wa + 8 * i;
        const bool tv = (tt < NT);
        const int ru = tt * 4 + (mb >> 2);
        const bool rv = tv && (ru < HID);
        const int R = gidx * HID + ru;       // original gate-major W row
        if (!grpB) {
#pragma unroll
            for (int kt = 0; kt < 2; ++kt) {
                v8h f;
#pragma unroll
                for (int j = 0; j < 8; ++j) {
                    const int kk = kt * 32 + q * 8 + j;
                    float v = 0.0f;
                    if (rv) {
                        if (kk < 4) v = w_ih1[R * 4 + kk];
                        else if (kk < 54) v = w_hh1[R * HID + (kk - 4)];
                    }
                    f[j] = (f16)(v * sc);
                }
                Af[i][kt] = f;
            }
        } else {
#pragma unroll
            for (int kt = 0; kt < 4; ++kt) {
                v8h f;
#pragma unroll
                for (int j = 0; j < 8; ++j) {
                    const int kk = kt * 32 + q * 8 + j;
                    float v = 0.0f;
                    if (rv) {
                        if (kk < HID) v = w_ih2[R * HID + kk];
                        else if (kk < 2 * HID) v = w_hh2[R * HID + (kk - HID)];
                    }
                    f[j] = (f16)(v * sc);
                }
                Af[i][kt] = f;
            }
        }
    }

    // ---- bias accumulators (C-in): reg r = gate r, unit = tile*4+q ----
    v4f bias0 = {0.f, 0.f, 0.f, 0.f}, bias1 = {0.f, 0.f, 0.f, 0.f};
#pragma unroll
    for (int r = 0; r < 4; ++r) {
        const float scr = (r == 2) ? (2.0f * LOG2E) : (-LOG2E);
        const int u0 = wa * 4 + q;
        const int u1t = (wa + 8) * 4 + q;
        const float* bi = grpB ? b_ih2 : b_ih1;
        const float* bh = grpB ? b_hh2 : b_hh1;
        if (u0 < HID) bias0[r] = (bi[r * HID + u0] + bh[r * HID + u0]) * scr;
        if ((wa + 8) < NT && u1t < HID)
            bias1[r] = (bi[r * HID + u1t] + bh[r * HID + u1t]) * scr;
    }
    const float wfc_me = (grpB && valid_upd) ? w_fc[u_me] : 0.0f;
    const float bfc = b_fc[0];
    float c_me = 0.0f;                // L1 cell (waves 0-7) / L2 cell (waves 8-15)

    // ---- LDS init + x preload ----
    for (int idx = tid; idx < 2 * BB * S1H; idx += NTHR) ((f16*)u1h)[idx] = (f16)0.0f;
    for (int idx = tid; idx < 2 * BB * S2H; idx += NTHR) ((f16*)u2h)[idx] = (f16)0.0f;
    ((float*)fcw)[tid] = 0.0f;        // 2*8*64 = 1024 == NTHR
    for (int i = tid; i < SEQ * BB; i += NTHR) {   // 4 iters, coalesced
        const int t = i >> 3, b = i & 7;
        const float4 v = *reinterpret_cast<const float4*>(
            x + ((size_t)t * BATCH + bbase + b) * 4);
        f16 p[4] = {(f16)v.x, (f16)v.y, (f16)v.z, (f16)v.w};
        *reinterpret_cast<uint2*>(&xl[t][b * 4]) = *reinterpret_cast<uint2*>(p);
    }
    __syncthreads();
    if (tid < BB) {   // x(0) -> u1 parity 0
        *reinterpret_cast<uint2*>(&u1h[0][tid * S1H]) =
            *reinterpret_cast<const uint2*>(&xl[0][tid * 4]);
    }
    __syncthreads();

    // ---- static wave priority: heavy (2-tile) waves preferred (T5) ----
    if (heavy) __builtin_amdgcn_s_setprio(1);

    // ---- hoisted per-parity LDS pointers ----
    const f16* u1rp[2] = {u1h[0] + b_me * S1H, u1h[1] + b_me * S1H};
    const f16* u2rp[2] = {u2h[0] + b_me * S2H, u2h[1] + b_me * S2H};
    f16* u1wp[2] = {u1h[0] + b_me * S1H, u1h[1] + b_me * S1H};
    f16* u2wp[2] = {u2h[0] + b_me * S2H, u2h[1] + b_me * S2H};

    // ---- superstep body (pr/pn become literals in the 2x-unrolled loop) ----
    auto body = [&](int s, int pr, int pn) __attribute__((always_inline)) {
        if (!grpB) {
            // ---------- L1 gates(t=s) ----------
            const f16* u1r = u1rp[pr];
            const v8h B0 = *reinterpret_cast<const v8h*>(&u1r[q * 8]);
            const v8h B1 = *reinterpret_cast<const v8h*>(&u1r[32 + q * 8]);
            v4f a0 = bias0;
            a0 = MFMA(Af[0][0], B0, a0);
            a0 = MFMA(Af[0][1], B1, a0);
            v4f m = a0;
            if (heavy) {               // wave-uniform; hi lanes pick tile wa+8
                v4f a1 = bias1;
                a1 = MFMA(Af[1][0], B0, a1);
                a1 = MFMA(Af[1][1], B1, a1);
                if (hiHalf) m = a1;
            }
            const float A  = 1.0f + EXP2F(m[0]);
            const float F  = 1.0f + EXP2F(m[1]);
            const float Bv = 1.0f + EXP2F(m[2]);
            const float C  = 1.0f + EXP2F(m[3]);
            const float AB = A * Bv;
            c_me = (c_me * AB + (Bv - 2.0f) * F) * RCPF(F * AB);
            const float D = 1.0f + EXP2F(c_me * (2.0f * LOG2E));
            const float h1v = (D - 2.0f) * RCPF(C * D);
            if (valid_upd) {
                u1wp[pn][4 + u_me] = (f16)h1v;
                u2wp[pr][u_me] = (f16)fmaxf(h1v, 0.0f);
            }
            // ---------- out reduce+store for t=s-2 (light wave 6) ----------
            if (wv == 6 && s >= 2) {
                float v = 0.0f;
#pragma unroll
                for (int k2 = 0; k2 < 8; ++k2) v += fcw[pn][k2][lane];
                v += __shfl_xor(v, 8);     // merge lo/hi tile halves (same batch)
                v += __shfl_xor(v, 16);    // merge quads
                v += __shfl_xor(v, 32);
                if (lane < BB) outb[s - 2][lane] = v + bfc;
            }
        } else {
            // ---------- x(s+1) staging: LDS -> LDS (light wave 8) ----------
            if (wv == 8 && lane < BB) {
                const int tn = (s + 1 < SEQ) ? s + 1 : SEQ - 1;
                *reinterpret_cast<uint2*>(&u1h[pn][lane * S1H]) =
                    *reinterpret_cast<const uint2*>(&xl[tn][lane * 4]);
            }
            // ---------- L2 gates(t=s-1) ----------
            const f16* u2r = u2rp[pn];
            const v8h C0 = *reinterpret_cast<const v8h*>(&u2r[q * 8]);
            const v8h C1 = *reinterpret_cast<const v8h*>(&u2r[32 + q * 8]);
            const v8h C2 = *reinterpret_cast<const v8h*>(&u2r[64 + q * 8]);
            const v8h C3 = *reinterpret_cast<const v8h*>(&u2r[96 + q * 8]);
            v4f a0 = bias0;
            a0 = MFMA(Af[0][0], C0, a0);
            a0 = MFMA(Af[0][1], C1, a0);
            a0 = MFMA(Af[0][2], C2, a0);
            a0 = MFMA(Af[0][3], C3, a0);
            v4f m = a0;
            if (heavy) {               // wave-uniform; hi lanes pick tile wa+8
                v4f a1 = bias1;
                a1 = MFMA(Af[1][0], C0, a1);
                a1 = MFMA(Af[1][1], C1, a1);
                a1 = MFMA(Af[1][2], C2, a1);
                a1 = MFMA(Af[1][3], C3, a1);
                if (hiHalf) m = a1;
            }
            const float A  = 1.0f + EXP2F(m[0]);
            const float F  = 1.0f + EXP2F(m[1]);
            const float Bv = 1.0f + EXP2F(m[2]);
            const float C  = 1.0f + EXP2F(m[3]);
            const float AB = A * Bv;
            const float cn = (c_me * AB + (Bv - 2.0f) * F) * RCPF(F * AB);
            const float D = 1.0f + EXP2F(cn * (2.0f * LOG2E));
            const float h2v = (D - 2.0f) * RCPF(C * D);
            float p = 0.0f;
            if (s >= 1) {                       // t=s-1 valid
                c_me = cn;
                if (valid_upd) u2wp[pr][HID + u_me] = (f16)h2v;
                p = fmaxf(h2v, 0.0f) * wfc_me;  // wfc_me=0 on invalid lanes
            }
            fcw[pr][wv - 8][lane] = p;          // RAW partial, no shfl tail
        }
        __syncthreads();   // the ONE barrier per superstep
    };

    // ---- pipelined supersteps, unrolled x2 (SEQ+2 = 514 is even) ----
#pragma unroll 1
    for (int s = 0; s < SEQ + 2; s += 2) {
        body(s, 0, 1);
        body(s + 1, 1, 0);
    }

    // ---- epilogue: flush outb -> global ----
    {
        const int i = tid;                 // SEQ*2 == 1024 == NTHR
        const int t = i >> 1, hb = (i & 1) * 4;
        *reinterpret_cast<float4*>(out + (size_t)t * BATCH + bbase + hb) =
            *reinterpret_cast<const float4*>(&outb[t][hb]);
    }
}

extern "C" void kernel_launch(void* const* d_in, const int* in_sizes, int n_in,
                              void* d_out, int out_size, void* d_ws, size_t ws_size,
                              hipStream_t stream) {
    const float* X    = (const float*)d_in[0];
    const float* Wih1 = (const float*)d_in[1];
    const float* Whh1 = (const float*)d_in[2];
    const float* Bih1 = (const float*)d_in[3];
    const float* Bhh1 = (const float*)d_in[4];
    const float* Wih2 = (const float*)d_in[5];
    const float* Whh2 = (const float*)d_in[6];
    const float* Bih2 = (const float*)d_in[7];
    const float* Bhh2 = (const float*)d_in[8];
    const float* Wfc  = (const float*)d_in[9];
    const float* Bfc  = (const float*)d_in[10];
    float* out = (float*)d_out;

    lstm2_fused<<<dim3(NBLK), dim3(NTHR), 0, stream>>>(
        X, Wih1, Whh1, Bih1, Bhh1, Wih2, Whh2, Bih2, Bhh2, Wfc, Bfc, out);
}